// Round 2
// baseline (922.970 us; speedup 1.0000x reference)
//
#include <hip/hip_runtime.h>
#include <math.h>

#define HEADS1 4
#define HID 64
#define LSTM_H 32
#define IN_F 128
#define T_STEPS 50
#define NEG_SLOPE 0.2f
#define EPS_A 1e-16f

typedef __attribute__((ext_vector_type(8))) short short8;
typedef __attribute__((ext_vector_type(4))) float floatx4;
typedef __attribute__((ext_vector_type(4))) unsigned uint32x4;

// ---------- helpers ----------
__device__ __forceinline__ float sigf(float x) { return 1.0f / (1.0f + __expf(-x)); }
__device__ __forceinline__ float tanhfast(float x) {
    float e = __expf(2.0f * x);
    return 1.0f - 2.0f / (e + 1.0f);
}
__device__ __forceinline__ unsigned short f2bf(float f) {
    unsigned u = __float_as_uint(f);
    unsigned r = (u + 0x7FFFu + ((u >> 16) & 1u)) >> 16;
    return (unsigned short)r;
}
__device__ __forceinline__ float bf2f(unsigned short s) {
    return __uint_as_float(((unsigned)s) << 16);
}
// HW packed fp32->bf16 (2 values / instruction); no builtin on gfx950, inline asm.
__device__ __forceinline__ unsigned cvt_pk_bf16(float a, float b) {
    unsigned r;
    asm("v_cvt_pk_bf16_f32 %0, %1, %2" : "=v"(r) : "v"(a), "v"(b));
    return r;
}
__device__ __forceinline__ float lo16f(unsigned p) { return __uint_as_float(p << 16); }
__device__ __forceinline__ float hi16f(unsigned p) { return __uint_as_float(p & 0xffff0000u); }

// ---------- GEMM: C[M,NC] = A[M,K] @ B[K,NC]; 64x64 tile, 4x4 micro ----------
template <int K, int NC>
__global__ __launch_bounds__(256) void gemm64(const float* __restrict__ A,
                                              const float* __restrict__ B,
                                              float* __restrict__ C, int M) {
    constexpr int KC = 32;
    __shared__ float As[KC][68];
    __shared__ float Bs[KC][64];
    const int row0 = blockIdx.x * 64;
    const int col0 = blockIdx.y * 64;
    const int tx = threadIdx.x & 15;
    const int ty = threadIdx.x >> 4;
    float acc[4][4] = {{0.f}};

    for (int k0 = 0; k0 < K; k0 += KC) {
        {
            const int kk = threadIdx.x & 31;
            const int rb = threadIdx.x >> 5;
#pragma unroll
            for (int r = 0; r < 8; r++) {
                int row = row0 + rb + r * 8;
                As[kk][rb + r * 8] = (row < M) ? A[(size_t)row * K + k0 + kk] : 0.0f;
            }
            const int c  = threadIdx.x & 63;
            const int kb = threadIdx.x >> 6;
#pragma unroll
            for (int q = 0; q < KC / 4; q++)
                Bs[kb + q * 4][c] = B[(size_t)(k0 + kb + q * 4) * NC + col0 + c];
        }
        __syncthreads();
#pragma unroll
        for (int kk = 0; kk < KC; kk++) {
            float4 a4 = *(const float4*)&As[kk][ty * 4];
            float4 b4 = *(const float4*)&Bs[kk][tx * 4];
            float av[4] = {a4.x, a4.y, a4.z, a4.w};
            float bv[4] = {b4.x, b4.y, b4.z, b4.w};
#pragma unroll
            for (int i = 0; i < 4; i++)
#pragma unroll
                for (int j = 0; j < 4; j++) acc[i][j] += av[i] * bv[j];
        }
        __syncthreads();
    }
#pragma unroll
    for (int i = 0; i < 4; i++) {
        int row = row0 + ty * 4 + i;
        if (row < M) {
            float4 v = make_float4(acc[i][0], acc[i][1], acc[i][2], acc[i][3]);
            *(float4*)&C[(size_t)row * NC + col0 + tx * 4] = v;
        }
    }
}

// ---------- attention scores ----------
__global__ void att_scores(const float* __restrict__ h, const float* __restrict__ att_s,
                           const float* __restrict__ att_d, float* __restrict__ as_,
                           float* __restrict__ ad_, int NH, int Hmask) {
    int i = blockIdx.x * blockDim.x + threadIdx.x;
    if (i >= NH) return;
    int hh = i & Hmask;
    const float* row = h + (size_t)i * HID;
    float s = 0.0f, d = 0.0f;
#pragma unroll 8
    for (int c = 0; c < HID; c++) {
        float v = row[c];
        s += v * att_s[hh * HID + c];
        d += v * att_d[hh * HID + c];
    }
    as_[i] = s;
    ad_[i] = d;
}

// ---------- CSR build ----------
__global__ void count_deg(const int* __restrict__ dsts, int E, int ET, int* __restrict__ cnt) {
    int e = blockIdx.x * blockDim.x + threadIdx.x;
    if (e >= ET) return;
    int d = (e < E) ? dsts[e] : (e - E);
    atomicAdd(&cnt[d], 1);
}

__global__ void scan1(const int* __restrict__ cnt, int* __restrict__ rowp,
                      int* __restrict__ bsum, int N) {
    __shared__ int tmp[256];
    int i = blockIdx.x * 256 + threadIdx.x;
    int v = (i < N) ? cnt[i] : 0;
    tmp[threadIdx.x] = v;
    __syncthreads();
    for (int off = 1; off < 256; off <<= 1) {
        int t = (threadIdx.x >= (unsigned)off) ? tmp[threadIdx.x - off] : 0;
        __syncthreads();
        tmp[threadIdx.x] += t;
        __syncthreads();
    }
    if (i < N) rowp[i] = tmp[threadIdx.x] - v;
    if (threadIdx.x == 255) bsum[blockIdx.x] = tmp[255];
}

__global__ void scan2(int* __restrict__ bsum, int nb) {
    __shared__ int tmp[256];
    int v = (threadIdx.x < (unsigned)nb) ? bsum[threadIdx.x] : 0;
    tmp[threadIdx.x] = v;
    __syncthreads();
    for (int off = 1; off < 256; off <<= 1) {
        int t = (threadIdx.x >= (unsigned)off) ? tmp[threadIdx.x - off] : 0;
        __syncthreads();
        tmp[threadIdx.x] += t;
        __syncthreads();
    }
    if (threadIdx.x < (unsigned)nb) bsum[threadIdx.x] = tmp[threadIdx.x] - v;
}

__global__ void scan3(int* __restrict__ rowp, const int* __restrict__ bsum, int N, int ET) {
    int i = blockIdx.x * 256 + threadIdx.x;
    if (i < N) rowp[i] += bsum[blockIdx.x];
    if (i == 0) rowp[N] = ET;
}

__global__ void scatter_edges(const int* __restrict__ dsts, int E, int ET,
                              const int* __restrict__ rowp, int* __restrict__ cursor,
                              int* __restrict__ eid) {
    int e = blockIdx.x * blockDim.x + threadIdx.x;
    if (e >= ET) return;
    int d = (e < E) ? dsts[e] : (e - E);
    int pos = atomicAdd(&cursor[d], 1);
    eid[rowp[d] + pos] = e;
}

// ---------- GAT layer-1 aggregation: single pass, one wave per dst, 4 heads ----------
// Scores are O(1) => exp without segment-max is numerically identical.
__global__ __launch_bounds__(256)
void gat_agg4_sp(const int* __restrict__ srcs, int E,
                 const int* __restrict__ rowp, const int* __restrict__ eid,
                 const float* __restrict__ as_, const float* __restrict__ ad_,
                 const float* __restrict__ hfeat, const float* __restrict__ bias,
                 float* __restrict__ g, int N) {
    __shared__ float s_alpha[4][64][4];
    const int wave = threadIdx.x >> 6;
    const int lane = threadIdx.x & 63;
    const int head = lane >> 4;
    const int dst = blockIdx.x * 4 + wave;
    if (dst >= N) return;
    const int start = rowp[dst], end = rowp[dst + 1];
    const float4 adv = ((const float4*)ad_)[dst];
    const float4* h4 = (const float4*)hfeat;

    float4 dsum = make_float4(0.f, 0.f, 0.f, 0.f);
    float4 acc  = make_float4(0.f, 0.f, 0.f, 0.f);

    for (int i0 = start; i0 < end; i0 += 64) {
        int cnt = min(64, end - i0);
        int i = i0 + lane;
        int s = 0;
        if (i < end) {
            int e = eid[i];
            s = (e < E) ? srcs[e] : (e - E);
            float4 a = ((const float4*)as_)[s];
            float tx, ex;
            tx = a.x + adv.x; tx = (tx > 0.f) ? tx : NEG_SLOPE * tx; ex = __expf(tx);
            dsum.x += ex; s_alpha[wave][lane][0] = ex;
            tx = a.y + adv.y; tx = (tx > 0.f) ? tx : NEG_SLOPE * tx; ex = __expf(tx);
            dsum.y += ex; s_alpha[wave][lane][1] = ex;
            tx = a.z + adv.z; tx = (tx > 0.f) ? tx : NEG_SLOPE * tx; ex = __expf(tx);
            dsum.z += ex; s_alpha[wave][lane][2] = ex;
            tx = a.w + adv.w; tx = (tx > 0.f) ? tx : NEG_SLOPE * tx; ex = __expf(tx);
            dsum.w += ex; s_alpha[wave][lane][3] = ex;
        }
        __builtin_amdgcn_wave_barrier();
#pragma unroll 4
        for (int k = 0; k < cnt; k++) {
            float a_k = s_alpha[wave][k][head];   // 16-lane broadcast read
            int   s_k = __shfl(s, k);
            float4 hv = h4[(size_t)s_k * 64 + lane];
            acc.x += a_k * hv.x; acc.y += a_k * hv.y;
            acc.z += a_k * hv.z; acc.w += a_k * hv.w;
        }
        __builtin_amdgcn_wave_barrier();
    }
#pragma unroll
    for (int mk = 32; mk >= 1; mk >>= 1) {
        dsum.x += __shfl_xor(dsum.x, mk);
        dsum.y += __shfl_xor(dsum.y, mk);
        dsum.z += __shfl_xor(dsum.z, mk);
        dsum.w += __shfl_xor(dsum.w, mk);
    }
    float den = (head == 0) ? dsum.x : (head == 1) ? dsum.y : (head == 2) ? dsum.z : dsum.w;
    float inv = 1.0f / (den + EPS_A);
    float4 b4 = ((const float4*)bias)[lane];
    float4 r;
    r.x = acc.x * inv + b4.x; r.x = (r.x > 0.f) ? r.x : __expf(r.x) - 1.f;
    r.y = acc.y * inv + b4.y; r.y = (r.y > 0.f) ? r.y : __expf(r.y) - 1.f;
    r.z = acc.z * inv + b4.z; r.z = (r.z > 0.f) ? r.z : __expf(r.z) - 1.f;
    r.w = acc.w * inv + b4.w; r.w = (r.w > 0.f) ? r.w : __expf(r.w) - 1.f;
    ((float4*)g)[(size_t)dst * 64 + lane] = r;
}

// ---------- GAT layer-2 aggregation: single pass, one wave per dst, H=1 ----------
__global__ __launch_bounds__(256)
void gat_agg1_sp(const int* __restrict__ srcs, int E,
                 const int* __restrict__ rowp, const int* __restrict__ eid,
                 const float* __restrict__ as_, const float* __restrict__ ad_,
                 const float* __restrict__ hfeat, const float* __restrict__ bias,
                 float* __restrict__ g, int N) {
    __shared__ float s_alpha[4][64];
    const int wave = threadIdx.x >> 6;
    const int lane = threadIdx.x & 63;
    const int dst = blockIdx.x * 4 + wave;
    if (dst >= N) return;
    const int start = rowp[dst], end = rowp[dst + 1];
    const float adv = ad_[dst];

    float dsum = 0.0f, acc = 0.0f;
    for (int i0 = start; i0 < end; i0 += 64) {
        int cnt = min(64, end - i0);
        int i = i0 + lane;
        int s = 0;
        if (i < end) {
            int e = eid[i];
            s = (e < E) ? srcs[e] : (e - E);
            float t = as_[s] + adv;
            t = (t > 0.f) ? t : NEG_SLOPE * t;
            float ex = __expf(t);
            dsum += ex;
            s_alpha[wave][lane] = ex;
        }
        __builtin_amdgcn_wave_barrier();
#pragma unroll 4
        for (int k = 0; k < cnt; k++) {
            float a_k = s_alpha[wave][k];         // full-wave broadcast read
            int   s_k = __shfl(s, k);
            acc += a_k * hfeat[(size_t)s_k * 64 + lane];
        }
        __builtin_amdgcn_wave_barrier();
    }
#pragma unroll
    for (int mk = 32; mk >= 1; mk >>= 1) dsum += __shfl_xor(dsum, mk);
    g[(size_t)dst * 64 + lane] = acc / (dsum + EPS_A) + bias[lane];
}

// ---------- LSTM via MFMA (split-bf16), round-10 ----------
// Delta vs round 9: gate-dimension split across wave PAIRS. Each 16-node tile
// is handled by 2 waves: sub=0 computes gate blocks {0,2,4,6} (i,f,g,o for
// h-units 0-15), sub=1 blocks {1,3,5,7} (units 16-31). Per-wave work per ts
// drops to 16 MFMA + 12 ds_read_b128 + half the gate transcendentals; total
// waves double (3.05 -> 6.1 per SIMD) to attack the latency-bound serial
// recurrence (r9 post-mortem: 15.5K cyc/ts wall vs ~1K cyc/ts of issue work).
// The pair exchanges h through a ping-pong LDS buffer (write buf[t&1], read
// buf[(t+1)&1]) with ONE __syncthreads per timestep. Block = 512 thr (4 pairs,
// 64 nodes); LDS 42KB -> 3 blocks/CU; __launch_bounds__(512,8) holds the
// <=64-reg budget needed for 8 waves/EU.
__global__ __launch_bounds__(512, 8)
void lstm_mfma(const float* __restrict__ seq, const float* __restrict__ Wih,
               const float* __restrict__ Whh, const float* __restrict__ bih,
               const float* __restrict__ bhh, float* __restrict__ t_out, int N) {
    __shared__ unsigned short sWhi[4096];   // lane-order swizzled (8 KB)
    __shared__ unsigned short sWlo[4096];
    __shared__ unsigned short sB2[4096];
    __shared__ float s_h[4][2][16][36];     // [pair][pingpong][node][unit+pad] 18 KB

    const int tid  = threadIdx.x;
    const int wave = tid >> 6, lane = tid & 63;
    const int pair = wave >> 1, sub = wave & 1;
    const int grp  = lane >> 4, col = lane & 15;
    const int node0 = blockIdx.x * 64 + pair * 16;

    // ---- stage Whh hi/lo, swizzled: slot i=(b*64+L)*8+j holds W[n=b*16+(L&15)][k=(L>>4)*8+j]
    for (int i = tid; i < 4096; i += 512) {
        int j = i & 7, L = (i >> 3) & 63, b = i >> 9;
        int n = b * 16 + (L & 15);
        int k = (L >> 4) * 8 + j;
        float v = Whh[n * 32 + k];
        unsigned short hi = f2bf(v);
        sWhi[i] = hi;
        sWlo[i] = f2bf(v - bf2f(hi));
    }
    // ---- stage B2 (x-path), same swizzle. B2[n][k]: k0-2 Wih_hi, 3 b_hi,
    //      k4-6 Wih_hi, 7 b_lo, k8-10 Wih_lo, rest 0.
    for (int i = tid; i < 4096; i += 512) {
        int j = i & 7, L = (i >> 3) & 63, b = i >> 9;
        int n = b * 16 + (L & 15);
        int k = (L >> 4) * 8 + j;
        unsigned short val = 0;
        if (k < 3) {
            val = f2bf(Wih[n * 3 + k]);
        } else if (k == 3) {
            val = f2bf(bih[n] + bhh[n]);
        } else if (k < 7) {
            val = f2bf(Wih[n * 3 + (k - 4)]);
        } else if (k == 7) {
            float bb = bih[n] + bhh[n];
            val = f2bf(bb - bf2f(f2bf(bb)));
        } else if (k < 11) {
            float wv = Wih[n * 3 + (k - 8)];
            val = f2bf(wv - bf2f(f2bf(wv)));
        }
        sB2[i] = val;
    }
    for (int i = tid; i < 4 * 2 * 16 * 36; i += 512) ((float*)s_h)[i] = 0.0f;
    __syncthreads();

    float cst[4] = {0.f, 0.f, 0.f, 0.f};
    float hnew[4] = {0.f, 0.f, 0.f, 0.f};
    const floatx4 zac = {0.f, 0.f, 0.f, 0.f};

    const int nodeX = node0 + col;
    const bool vx = (nodeX < N) && (grp < 2);
    const bool g0 = (grp == 0);
    const float* xp = seq + (size_t)nodeX * (T_STEPS * 3);

    // this wave's gate blocks: i,f,g,o for units [sub*16, sub*16+16)
    const int bl[4] = {sub, sub + 2, sub + 4, sub + 6};

    // x for t=0
    float xv0 = vx ? xp[0] : 0.0f;
    float xv1 = vx ? xp[1] : 0.0f;
    float xv2 = vx ? xp[2] : 0.0f;

#pragma unroll 1
    for (int t = 0; t < T_STEPS; t++) {
        // ---- A2: x hi/lo + ones in K-slots (grp0: k'0-7, grp1: k'8-10) ----
        unsigned w0 = cvt_pk_bf16(xv0, xv1);
        unsigned w1 = cvt_pk_bf16(xv2, g0 ? 1.0f : 0.0f);
        float e0 = xv0 - lo16f(w0);
        float e1 = xv1 - hi16f(w0);
        float e2 = xv2 - lo16f(w1);
        unsigned w2 = g0 ? cvt_pk_bf16(e0, e1) : 0u;
        unsigned w3 = g0 ? cvt_pk_bf16(e2, 1.0f) : 0u;
        uint32x4 a2p = {w0, w1, w2, w3};
        short8 A2 = __builtin_bit_cast(short8, a2p);

        // ---- A (h) hi/lo from ping-pong LDS (prev buffer; t=0 reads zeros) ----
        const float* hr = &s_h[pair][(t + 1) & 1][col][grp * 8];
        floatx4 h0 = *(const floatx4*)&hr[0];
        floatx4 h1 = *(const floatx4*)&hr[4];
        unsigned p0 = cvt_pk_bf16(h0[0], h0[1]);
        unsigned p1 = cvt_pk_bf16(h0[2], h0[3]);
        unsigned p2 = cvt_pk_bf16(h1[0], h1[1]);
        unsigned p3 = cvt_pk_bf16(h1[2], h1[3]);
        uint32x4 hip = {p0, p1, p2, p3};
        short8 Ahi = __builtin_bit_cast(short8, hip);
        unsigned q0 = cvt_pk_bf16(h0[0] - lo16f(p0), h0[1] - hi16f(p0));
        unsigned q1 = cvt_pk_bf16(h0[2] - lo16f(p1), h0[3] - hi16f(p1));
        unsigned q2 = cvt_pk_bf16(h1[0] - lo16f(p2), h1[1] - hi16f(p2));
        unsigned q3 = cvt_pk_bf16(h1[2] - lo16f(p3), h1[3] - hi16f(p3));
        uint32x4 lop = {q0, q1, q2, q3};
        short8 Alo = __builtin_bit_cast(short8, lop);

        // ---- prefetch next x (clamped offset; hidden under MFMAs+gates) ----
        {
            int tn = (t + 1 < T_STEPS) ? (t + 1) : t;
            xv0 = vx ? xp[tn * 3 + 0] : 0.0f;
            xv1 = vx ? xp[tn * 3 + 1] : 0.0f;
            xv2 = vx ? xp[tn * 3 + 2] : 0.0f;
        }

        // ---- this wave's 4 gate-blocks x 4 MFMAs ----
        floatx4 acc[4];
#pragma unroll
        for (int kk = 0; kk < 4; kk++) {
            int b = bl[kk];
            short8 B2f = *(const short8*)&sB2[(b * 64 + lane) * 8];
            short8 Bhi = *(const short8*)&sWhi[(b * 64 + lane) * 8];
            short8 Blo = *(const short8*)&sWlo[(b * 64 + lane) * 8];
            floatx4 d = __builtin_amdgcn_mfma_f32_16x16x32_bf16(A2, B2f, zac, 0, 0, 0);
            d = __builtin_amdgcn_mfma_f32_16x16x32_bf16(Alo, Bhi, d, 0, 0, 0);
            d = __builtin_amdgcn_mfma_f32_16x16x32_bf16(Ahi, Blo, d, 0, 0, 0);
            acc[kk] = __builtin_amdgcn_mfma_f32_16x16x32_bf16(Ahi, Bhi, d, 0, 0, 0);
        }

        // ---- gates (this wave's 16 units only) ----
#pragma unroll
        for (int q = 0; q < 4; q++) {
            float ig = sigf(acc[0][q]), fg = sigf(acc[1][q]);
            float gv = tanhfast(acc[2][q]), og = sigf(acc[3][q]);
            cst[q] = fg * cst[q] + ig * gv;
            hnew[q] = og * tanhfast(cst[q]);
        }

        // ---- h writeback to ping-pong buffer, then pair-visible barrier ----
#pragma unroll
        for (int q = 0; q < 4; q++)
            s_h[pair][t & 1][4 * grp + q][sub * 16 + col] = hnew[q];
        __syncthreads();
    }

#pragma unroll
    for (int q = 0; q < 4; q++) {
        int node = node0 + 4 * grp + q;
        if (node < N) t_out[(size_t)node * LSTM_H + sub * 16 + col] = hnew[q];
    }
}

// ---------- fusion MLP ----------
__global__ void fusion_kernel(const float* __restrict__ g2, const float* __restrict__ tt,
                              const float* __restrict__ Wf1, const float* __restrict__ bf1,
                              const float* __restrict__ Wf2, const float* __restrict__ bf2,
                              float* __restrict__ out, int N) {
    __shared__ float sW[96 * 64];
    __shared__ float sb1[64];
    __shared__ float sW2[128];
    for (int i = threadIdx.x; i < 96 * 64; i += 256) sW[i] = Wf1[i];
    if (threadIdx.x < 64) sb1[threadIdx.x] = bf1[threadIdx.x];
    if (threadIdx.x < 128) sW2[threadIdx.x] = Wf2[threadIdx.x];
    __syncthreads();
    const int wave = threadIdx.x >> 6;
    const int lane = threadIdx.x & 63;
    for (int n = blockIdx.x * 4 + wave; n < N; n += gridDim.x * 4) {
        const float* gn = g2 + (size_t)n * 64;
        const float* tn = tt + (size_t)n * 32;
        float acc = sb1[lane];
#pragma unroll 8
        for (int k = 0; k < 64; k++) acc += gn[k] * sW[k * 64 + lane];
#pragma unroll 8
        for (int k = 0; k < 32; k++) acc += tn[k] * sW[(64 + k) * 64 + lane];
        acc = fmaxf(acc, 0.0f);
        float o0 = acc * sW2[lane * 2 + 0];
        float o1 = acc * sW2[lane * 2 + 1];
#pragma unroll
        for (int mk = 32; mk >= 1; mk >>= 1) {
            o0 += __shfl_xor(o0, mk);
            o1 += __shfl_xor(o1, mk);
        }
        if (lane == 0) {
            out[(size_t)n * 2 + 0] = o0 + bf2[0];
            out[(size_t)n * 2 + 1] = o1 + bf2[1];
        }
    }
}

extern "C" void kernel_launch(void* const* d_in, const int* in_sizes, int n_in,
                              void* d_out, int out_size, void* d_ws, size_t ws_size,
                              hipStream_t stream) {
    const float* x      = (const float*)d_in[0];
    const int*   eidx   = (const int*)d_in[1];
    const float* seq    = (const float*)d_in[2];
    const float* W1     = (const float*)d_in[3];
    const float* att_s1 = (const float*)d_in[4];
    const float* att_d1 = (const float*)d_in[5];
    const float* bias1  = (const float*)d_in[6];
    const float* W2     = (const float*)d_in[7];
    const float* att_s2 = (const float*)d_in[8];
    const float* att_d2 = (const float*)d_in[9];
    const float* bias2  = (const float*)d_in[10];
    const float* Wih    = (const float*)d_in[11];
    const float* Whh    = (const float*)d_in[12];
    const float* bih    = (const float*)d_in[13];
    const float* bhh    = (const float*)d_in[14];
    const float* Wf1    = (const float*)d_in[15];
    const float* bf1    = (const float*)d_in[16];
    const float* Wf2    = (const float*)d_in[17];
    const float* bf2    = (const float*)d_in[18];
    float* out = (float*)d_out;

    const int N  = in_sizes[0] / IN_F;   // 50000
    const int E  = in_sizes[1] / 2;      // 800000
    const int ET = E + N;
    const int* srcs = eidx;
    const int* dsts = eidx + E;

    // workspace layout
    float* fws = (float*)d_ws;
    size_t o = 0;
    float* h1  = fws + o; o += (size_t)N * 256;
    float* g1  = fws + o; o += (size_t)N * 256;
    float* as1 = fws + o; o += (size_t)N * 4;
    float* ad1 = fws + o; o += (size_t)N * 4;
    int* cnt    = (int*)(fws + o);
    int* rowp   = cnt + N;
    int* cursor = rowp + N + 1;
    int* eid    = cursor + N;
    int* bsum   = eid + ET;
    // layer-2 / LSTM aliases (h1 region dead after layer-1 aggregation)
    float* h2 = h1;                      // N*64
    float* g2 = h1 + (size_t)N * 64;     // N*64
    float* tt = h1 + (size_t)N * 128;    // N*32
    float* as2 = as1; float* ad2 = ad1;

    const int nTiles = (N + 255) / 256;
    dim3 blk(256);

    // ---- CSR build ----
    hipMemsetAsync(cnt, 0, (size_t)N * sizeof(int), stream);
    hipMemsetAsync(cursor, 0, (size_t)N * sizeof(int), stream);
    count_deg<<<(ET + 255) / 256, blk, 0, stream>>>(dsts, E, ET, cnt);
    scan1<<<nTiles, blk, 0, stream>>>(cnt, rowp, bsum, N);
    scan2<<<1, blk, 0, stream>>>(bsum, nTiles);
    scan3<<<(N + 256) / 256, blk, 0, stream>>>(rowp, bsum, N, ET);
    scatter_edges<<<(ET + 255) / 256, blk, 0, stream>>>(dsts, E, ET, rowp, cursor, eid);

    // ---- GAT layer 1 ----
    gemm64<128, 256><<<dim3((N + 63) / 64, 4), blk, 0, stream>>>(x, W1, h1, N);
    att_scores<<<(N * 4 + 255) / 256, blk, 0, stream>>>(h1, att_s1, att_d1, as1, ad1, N * 4, 3);
    gat_agg4_sp<<<(N + 3) / 4, blk, 0, stream>>>(srcs, E, rowp, eid, as1, ad1, h1, bias1, g1, N);

    // ---- LSTM (MFMA; gate-split wave pairs; tt region free once layer-1 agg done) ----
    lstm_mfma<<<(N + 63) / 64, dim3(512), 0, stream>>>(seq, Wih, Whh, bih, bhh, tt, N);

    // ---- GAT layer 2 ----
    gemm64<256, 64><<<dim3((N + 63) / 64, 1), blk, 0, stream>>>(g1, W2, h2, N);
    att_scores<<<(N + 255) / 256, blk, 0, stream>>>(h2, att_s2, att_d2, as2, ad2, N, 0);
    gat_agg1_sp<<<(N + 3) / 4, blk, 0, stream>>>(srcs, E, rowp, eid, as2, ad2, h2, bias2, g2, N);

    // ---- fusion MLP ----
    fusion_kernel<<<512, blk, 0, stream>>>(g2, tt, Wf1, bf1, Wf2, bf2, out, N);
}

// Round 3
// 882.802 us; speedup vs baseline: 1.0455x; 1.0455x over previous
//
#include <hip/hip_runtime.h>
#include <math.h>

#define HEADS1 4
#define HID 64
#define LSTM_H 32
#define IN_F 128
#define T_STEPS 50
#define NEG_SLOPE 0.2f
#define EPS_A 1e-16f

typedef __attribute__((ext_vector_type(8))) short short8;
typedef __attribute__((ext_vector_type(4))) float floatx4;
typedef __attribute__((ext_vector_type(4))) unsigned uint32x4;

// ---------- helpers ----------
__device__ __forceinline__ float sigf(float x) { return 1.0f / (1.0f + __expf(-x)); }
__device__ __forceinline__ float tanhfast(float x) {
    float e = __expf(2.0f * x);
    return 1.0f - 2.0f / (e + 1.0f);
}
__device__ __forceinline__ unsigned short f2bf(float f) {
    unsigned u = __float_as_uint(f);
    unsigned r = (u + 0x7FFFu + ((u >> 16) & 1u)) >> 16;
    return (unsigned short)r;
}
__device__ __forceinline__ float bf2f(unsigned short s) {
    return __uint_as_float(((unsigned)s) << 16);
}
// HW packed fp32->bf16 (2 values / instruction); no builtin on gfx950, inline asm.
__device__ __forceinline__ unsigned cvt_pk_bf16(float a, float b) {
    unsigned r;
    asm("v_cvt_pk_bf16_f32 %0, %1, %2" : "=v"(r) : "v"(a), "v"(b));
    return r;
}
__device__ __forceinline__ float lo16f(unsigned p) { return __uint_as_float(p << 16); }
__device__ __forceinline__ float hi16f(unsigned p) { return __uint_as_float(p & 0xffff0000u); }

// ---------- GEMM: C[M,NC] = A[M,K] @ B[K,NC]; 64x64 tile, 4x4 micro ----------
template <int K, int NC>
__global__ __launch_bounds__(256) void gemm64(const float* __restrict__ A,
                                              const float* __restrict__ B,
                                              float* __restrict__ C, int M) {
    constexpr int KC = 32;
    __shared__ float As[KC][68];
    __shared__ float Bs[KC][64];
    const int row0 = blockIdx.x * 64;
    const int col0 = blockIdx.y * 64;
    const int tx = threadIdx.x & 15;
    const int ty = threadIdx.x >> 4;
    float acc[4][4] = {{0.f}};

    for (int k0 = 0; k0 < K; k0 += KC) {
        {
            const int kk = threadIdx.x & 31;
            const int rb = threadIdx.x >> 5;
#pragma unroll
            for (int r = 0; r < 8; r++) {
                int row = row0 + rb + r * 8;
                As[kk][rb + r * 8] = (row < M) ? A[(size_t)row * K + k0 + kk] : 0.0f;
            }
            const int c  = threadIdx.x & 63;
            const int kb = threadIdx.x >> 6;
#pragma unroll
            for (int q = 0; q < KC / 4; q++)
                Bs[kb + q * 4][c] = B[(size_t)(k0 + kb + q * 4) * NC + col0 + c];
        }
        __syncthreads();
#pragma unroll
        for (int kk = 0; kk < KC; kk++) {
            float4 a4 = *(const float4*)&As[kk][ty * 4];
            float4 b4 = *(const float4*)&Bs[kk][tx * 4];
            float av[4] = {a4.x, a4.y, a4.z, a4.w};
            float bv[4] = {b4.x, b4.y, b4.z, b4.w};
#pragma unroll
            for (int i = 0; i < 4; i++)
#pragma unroll
                for (int j = 0; j < 4; j++) acc[i][j] += av[i] * bv[j];
        }
        __syncthreads();
    }
#pragma unroll
    for (int i = 0; i < 4; i++) {
        int row = row0 + ty * 4 + i;
        if (row < M) {
            float4 v = make_float4(acc[i][0], acc[i][1], acc[i][2], acc[i][3]);
            *(float4*)&C[(size_t)row * NC + col0 + tx * 4] = v;
        }
    }
}

// ---------- attention scores ----------
__global__ void att_scores(const float* __restrict__ h, const float* __restrict__ att_s,
                           const float* __restrict__ att_d, float* __restrict__ as_,
                           float* __restrict__ ad_, int NH, int Hmask) {
    int i = blockIdx.x * blockDim.x + threadIdx.x;
    if (i >= NH) return;
    int hh = i & Hmask;
    const float* row = h + (size_t)i * HID;
    float s = 0.0f, d = 0.0f;
#pragma unroll 8
    for (int c = 0; c < HID; c++) {
        float v = row[c];
        s += v * att_s[hh * HID + c];
        d += v * att_d[hh * HID + c];
    }
    as_[i] = s;
    ad_[i] = d;
}

// ---------- CSR build ----------
__global__ void count_deg(const int* __restrict__ dsts, int E, int ET, int* __restrict__ cnt) {
    int e = blockIdx.x * blockDim.x + threadIdx.x;
    if (e >= ET) return;
    int d = (e < E) ? dsts[e] : (e - E);
    atomicAdd(&cnt[d], 1);
}

__global__ void scan1(const int* __restrict__ cnt, int* __restrict__ rowp,
                      int* __restrict__ bsum, int N) {
    __shared__ int tmp[256];
    int i = blockIdx.x * 256 + threadIdx.x;
    int v = (i < N) ? cnt[i] : 0;
    tmp[threadIdx.x] = v;
    __syncthreads();
    for (int off = 1; off < 256; off <<= 1) {
        int t = (threadIdx.x >= (unsigned)off) ? tmp[threadIdx.x - off] : 0;
        __syncthreads();
        tmp[threadIdx.x] += t;
        __syncthreads();
    }
    if (i < N) rowp[i] = tmp[threadIdx.x] - v;
    if (threadIdx.x == 255) bsum[blockIdx.x] = tmp[255];
}

__global__ void scan2(int* __restrict__ bsum, int nb) {
    __shared__ int tmp[256];
    int v = (threadIdx.x < (unsigned)nb) ? bsum[threadIdx.x] : 0;
    tmp[threadIdx.x] = v;
    __syncthreads();
    for (int off = 1; off < 256; off <<= 1) {
        int t = (threadIdx.x >= (unsigned)off) ? tmp[threadIdx.x - off] : 0;
        __syncthreads();
        tmp[threadIdx.x] += t;
        __syncthreads();
    }
    if (threadIdx.x < (unsigned)nb) bsum[threadIdx.x] = tmp[threadIdx.x] - v;
}

__global__ void scan3(int* __restrict__ rowp, const int* __restrict__ bsum, int N, int ET) {
    int i = blockIdx.x * 256 + threadIdx.x;
    if (i < N) rowp[i] += bsum[blockIdx.x];
    if (i == 0) rowp[N] = ET;
}

__global__ void scatter_edges(const int* __restrict__ dsts, int E, int ET,
                              const int* __restrict__ rowp, int* __restrict__ cursor,
                              int* __restrict__ eid) {
    int e = blockIdx.x * blockDim.x + threadIdx.x;
    if (e >= ET) return;
    int d = (e < E) ? dsts[e] : (e - E);
    int pos = atomicAdd(&cursor[d], 1);
    eid[rowp[d] + pos] = e;
}

// ---------- GAT layer-1 aggregation: single pass, one wave per dst, 4 heads ----------
// Scores are O(1) => exp without segment-max is numerically identical.
__global__ __launch_bounds__(256)
void gat_agg4_sp(const int* __restrict__ srcs, int E,
                 const int* __restrict__ rowp, const int* __restrict__ eid,
                 const float* __restrict__ as_, const float* __restrict__ ad_,
                 const float* __restrict__ hfeat, const float* __restrict__ bias,
                 float* __restrict__ g, int N) {
    __shared__ float s_alpha[4][64][4];
    const int wave = threadIdx.x >> 6;
    const int lane = threadIdx.x & 63;
    const int head = lane >> 4;
    const int dst = blockIdx.x * 4 + wave;
    if (dst >= N) return;
    const int start = rowp[dst], end = rowp[dst + 1];
    const float4 adv = ((const float4*)ad_)[dst];
    const float4* h4 = (const float4*)hfeat;

    float4 dsum = make_float4(0.f, 0.f, 0.f, 0.f);
    float4 acc  = make_float4(0.f, 0.f, 0.f, 0.f);

    for (int i0 = start; i0 < end; i0 += 64) {
        int cnt = min(64, end - i0);
        int i = i0 + lane;
        int s = 0;
        if (i < end) {
            int e = eid[i];
            s = (e < E) ? srcs[e] : (e - E);
            float4 a = ((const float4*)as_)[s];
            float tx, ex;
            tx = a.x + adv.x; tx = (tx > 0.f) ? tx : NEG_SLOPE * tx; ex = __expf(tx);
            dsum.x += ex; s_alpha[wave][lane][0] = ex;
            tx = a.y + adv.y; tx = (tx > 0.f) ? tx : NEG_SLOPE * tx; ex = __expf(tx);
            dsum.y += ex; s_alpha[wave][lane][1] = ex;
            tx = a.z + adv.z; tx = (tx > 0.f) ? tx : NEG_SLOPE * tx; ex = __expf(tx);
            dsum.z += ex; s_alpha[wave][lane][2] = ex;
            tx = a.w + adv.w; tx = (tx > 0.f) ? tx : NEG_SLOPE * tx; ex = __expf(tx);
            dsum.w += ex; s_alpha[wave][lane][3] = ex;
        }
        __builtin_amdgcn_wave_barrier();
#pragma unroll 4
        for (int k = 0; k < cnt; k++) {
            float a_k = s_alpha[wave][k][head];   // 16-lane broadcast read
            int   s_k = __shfl(s, k);
            float4 hv = h4[(size_t)s_k * 64 + lane];
            acc.x += a_k * hv.x; acc.y += a_k * hv.y;
            acc.z += a_k * hv.z; acc.w += a_k * hv.w;
        }
        __builtin_amdgcn_wave_barrier();
    }
#pragma unroll
    for (int mk = 32; mk >= 1; mk >>= 1) {
        dsum.x += __shfl_xor(dsum.x, mk);
        dsum.y += __shfl_xor(dsum.y, mk);
        dsum.z += __shfl_xor(dsum.z, mk);
        dsum.w += __shfl_xor(dsum.w, mk);
    }
    float den = (head == 0) ? dsum.x : (head == 1) ? dsum.y : (head == 2) ? dsum.z : dsum.w;
    float inv = 1.0f / (den + EPS_A);
    float4 b4 = ((const float4*)bias)[lane];
    float4 r;
    r.x = acc.x * inv + b4.x; r.x = (r.x > 0.f) ? r.x : __expf(r.x) - 1.f;
    r.y = acc.y * inv + b4.y; r.y = (r.y > 0.f) ? r.y : __expf(r.y) - 1.f;
    r.z = acc.z * inv + b4.z; r.z = (r.z > 0.f) ? r.z : __expf(r.z) - 1.f;
    r.w = acc.w * inv + b4.w; r.w = (r.w > 0.f) ? r.w : __expf(r.w) - 1.f;
    ((float4*)g)[(size_t)dst * 64 + lane] = r;
}

// ---------- GAT layer-2 aggregation: single pass, one wave per dst, H=1 ----------
__global__ __launch_bounds__(256)
void gat_agg1_sp(const int* __restrict__ srcs, int E,
                 const int* __restrict__ rowp, const int* __restrict__ eid,
                 const float* __restrict__ as_, const float* __restrict__ ad_,
                 const float* __restrict__ hfeat, const float* __restrict__ bias,
                 float* __restrict__ g, int N) {
    __shared__ float s_alpha[4][64];
    const int wave = threadIdx.x >> 6;
    const int lane = threadIdx.x & 63;
    const int dst = blockIdx.x * 4 + wave;
    if (dst >= N) return;
    const int start = rowp[dst], end = rowp[dst + 1];
    const float adv = ad_[dst];

    float dsum = 0.0f, acc = 0.0f;
    for (int i0 = start; i0 < end; i0 += 64) {
        int cnt = min(64, end - i0);
        int i = i0 + lane;
        int s = 0;
        if (i < end) {
            int e = eid[i];
            s = (e < E) ? srcs[e] : (e - E);
            float t = as_[s] + adv;
            t = (t > 0.f) ? t : NEG_SLOPE * t;
            float ex = __expf(t);
            dsum += ex;
            s_alpha[wave][lane] = ex;
        }
        __builtin_amdgcn_wave_barrier();
#pragma unroll 4
        for (int k = 0; k < cnt; k++) {
            float a_k = s_alpha[wave][k];         // full-wave broadcast read
            int   s_k = __shfl(s, k);
            acc += a_k * hfeat[(size_t)s_k * 64 + lane];
        }
        __builtin_amdgcn_wave_barrier();
    }
#pragma unroll
    for (int mk = 32; mk >= 1; mk >>= 1) dsum += __shfl_xor(dsum, mk);
    g[(size_t)dst * 64 + lane] = acc / (dsum + EPS_A) + bias[lane];
}

// ---------- LSTM via MFMA (split-bf16), round-11 ----------
// Delta vs round 10: weight fragments hoisted from LDS to REGISTERS (48 VGPR:
// 12 frags x 4 regs), built directly from global (each lane reads its own
// 8-float Whh row-chunk + 3 Wih floats + bias -- exactly the values the old
// LDS swizzle materialized). Kills the 12 loop-invariant ds_read_b128 per
// wave-ts (re-read 50x in r10 -> ~110us of LDS pipe), their lgkmcnt waits,
// the 3x8KB LDS weight buffers, and the 2.5M bank conflicts. LDS = 18KB
// h ping-pong only. r10 proved occupancy >20% buys nothing (latency theory
// dead), so the VGPR rise (40 -> ~120, 4 waves/SIMD) is free.
__global__ __launch_bounds__(512, 4)
void lstm_mfma(const float* __restrict__ seq, const float* __restrict__ Wih,
               const float* __restrict__ Whh, const float* __restrict__ bih,
               const float* __restrict__ bhh, float* __restrict__ t_out, int N) {
    __shared__ float s_h[4][2][16][36];     // [pair][pingpong][node][unit+pad] 18 KB

    const int tid  = threadIdx.x;
    const int wave = tid >> 6, lane = tid & 63;
    const int pair = wave >> 1, sub = wave & 1;
    const int grp  = lane >> 4, col = lane & 15;
    const int node0 = blockIdx.x * 64 + pair * 16;

    // ---- weight fragments -> registers (loop-invariant) ----
    // Fragment elem j of lane (grp,col) holds B[n = b*16+col][k' = grp*8+j].
    short8 B2f[4], Bhi[4], Blo[4];
#pragma unroll
    for (int kk = 0; kk < 4; kk++) {
        const int b = sub + kk * 2;          // this wave's gate blocks
        const int n = b * 16 + col;
        const int krow = grp * 8;
        float w[8];
        *(float4*)&w[0] = *(const float4*)&Whh[n * 32 + krow + 0];
        *(float4*)&w[4] = *(const float4*)&Whh[n * 32 + krow + 4];
        short8 hi8, lo8;
#pragma unroll
        for (int j = 0; j < 8; j++) {
            unsigned short h = f2bf(w[j]);
            hi8[j] = (short)h;
            lo8[j] = (short)f2bf(w[j] - bf2f(h));
        }
        Bhi[kk] = hi8;
        Blo[kk] = lo8;
        // B2 (x-path): k'0-2 Wih_hi, 3 bb_hi, k'4-6 Wih_hi, 7 bb_lo, k'8-10 Wih_lo.
        float wi0 = Wih[n * 3 + 0], wi1 = Wih[n * 3 + 1], wi2 = Wih[n * 3 + 2];
        float bb = bih[n] + bhh[n];
        unsigned short h0 = f2bf(wi0), h1 = f2bf(wi1), h2 = f2bf(wi2), hb = f2bf(bb);
        short8 b2 = {0, 0, 0, 0, 0, 0, 0, 0};
        if (grp == 0) {
            b2[0] = (short)h0; b2[1] = (short)h1; b2[2] = (short)h2; b2[3] = (short)hb;
            b2[4] = (short)h0; b2[5] = (short)h1; b2[6] = (short)h2;
            b2[7] = (short)f2bf(bb - bf2f(hb));
        } else if (grp == 1) {
            b2[0] = (short)f2bf(wi0 - bf2f(h0));
            b2[1] = (short)f2bf(wi1 - bf2f(h1));
            b2[2] = (short)f2bf(wi2 - bf2f(h2));
        }
        B2f[kk] = b2;
    }

    for (int i = tid; i < 4 * 2 * 16 * 36; i += 512) ((float*)s_h)[i] = 0.0f;
    __syncthreads();

    float cst[4] = {0.f, 0.f, 0.f, 0.f};
    float hnew[4] = {0.f, 0.f, 0.f, 0.f};
    const floatx4 zac = {0.f, 0.f, 0.f, 0.f};

    const int nodeX = node0 + col;
    const bool vx = (nodeX < N) && (grp < 2);
    const bool g0 = (grp == 0);
    const float* xp = seq + (size_t)nodeX * (T_STEPS * 3);

    // x for t=0
    float xv0 = vx ? xp[0] : 0.0f;
    float xv1 = vx ? xp[1] : 0.0f;
    float xv2 = vx ? xp[2] : 0.0f;

#pragma unroll 1
    for (int t = 0; t < T_STEPS; t++) {
        // ---- A2: x hi/lo + ones in K-slots (grp0: k'0-7, grp1: k'8-10) ----
        unsigned w0 = cvt_pk_bf16(xv0, xv1);
        unsigned w1 = cvt_pk_bf16(xv2, g0 ? 1.0f : 0.0f);
        float e0 = xv0 - lo16f(w0);
        float e1 = xv1 - hi16f(w0);
        float e2 = xv2 - lo16f(w1);
        unsigned w2 = g0 ? cvt_pk_bf16(e0, e1) : 0u;
        unsigned w3 = g0 ? cvt_pk_bf16(e2, 1.0f) : 0u;
        uint32x4 a2p = {w0, w1, w2, w3};
        short8 A2 = __builtin_bit_cast(short8, a2p);

        // ---- A (h) hi/lo from ping-pong LDS (prev buffer; t=0 reads zeros) ----
        const float* hr = &s_h[pair][(t + 1) & 1][col][grp * 8];
        floatx4 h0 = *(const floatx4*)&hr[0];
        floatx4 h1 = *(const floatx4*)&hr[4];
        unsigned p0 = cvt_pk_bf16(h0[0], h0[1]);
        unsigned p1 = cvt_pk_bf16(h0[2], h0[3]);
        unsigned p2 = cvt_pk_bf16(h1[0], h1[1]);
        unsigned p3 = cvt_pk_bf16(h1[2], h1[3]);
        uint32x4 hip = {p0, p1, p2, p3};
        short8 Ahi = __builtin_bit_cast(short8, hip);
        unsigned q0 = cvt_pk_bf16(h0[0] - lo16f(p0), h0[1] - hi16f(p0));
        unsigned q1 = cvt_pk_bf16(h0[2] - lo16f(p1), h0[3] - hi16f(p1));
        unsigned q2 = cvt_pk_bf16(h1[0] - lo16f(p2), h1[1] - hi16f(p2));
        unsigned q3 = cvt_pk_bf16(h1[2] - lo16f(p3), h1[3] - hi16f(p3));
        uint32x4 lop = {q0, q1, q2, q3};
        short8 Alo = __builtin_bit_cast(short8, lop);

        // ---- prefetch next x (clamped offset; hidden under MFMAs+gates) ----
        {
            int tn = (t + 1 < T_STEPS) ? (t + 1) : t;
            xv0 = vx ? xp[tn * 3 + 0] : 0.0f;
            xv1 = vx ? xp[tn * 3 + 1] : 0.0f;
            xv2 = vx ? xp[tn * 3 + 2] : 0.0f;
        }

        // ---- this wave's 4 gate-blocks x 4 MFMAs; all operands in registers ----
        floatx4 acc[4];
#pragma unroll
        for (int kk = 0; kk < 4; kk++) {
            floatx4 d = __builtin_amdgcn_mfma_f32_16x16x32_bf16(A2, B2f[kk], zac, 0, 0, 0);
            d = __builtin_amdgcn_mfma_f32_16x16x32_bf16(Alo, Bhi[kk], d, 0, 0, 0);
            d = __builtin_amdgcn_mfma_f32_16x16x32_bf16(Ahi, Blo[kk], d, 0, 0, 0);
            acc[kk] = __builtin_amdgcn_mfma_f32_16x16x32_bf16(Ahi, Bhi[kk], d, 0, 0, 0);
        }

        // ---- gates (this wave's 16 units only) ----
#pragma unroll
        for (int q = 0; q < 4; q++) {
            float ig = sigf(acc[0][q]), fg = sigf(acc[1][q]);
            float gv = tanhfast(acc[2][q]), og = sigf(acc[3][q]);
            cst[q] = fg * cst[q] + ig * gv;
            hnew[q] = og * tanhfast(cst[q]);
        }

        // ---- h writeback to ping-pong buffer, then pair-visible barrier ----
#pragma unroll
        for (int q = 0; q < 4; q++)
            s_h[pair][t & 1][4 * grp + q][sub * 16 + col] = hnew[q];
        __syncthreads();
    }

#pragma unroll
    for (int q = 0; q < 4; q++) {
        int node = node0 + 4 * grp + q;
        if (node < N) t_out[(size_t)node * LSTM_H + sub * 16 + col] = hnew[q];
    }
}

// ---------- fusion MLP ----------
__global__ void fusion_kernel(const float* __restrict__ g2, const float* __restrict__ tt,
                              const float* __restrict__ Wf1, const float* __restrict__ bf1,
                              const float* __restrict__ Wf2, const float* __restrict__ bf2,
                              float* __restrict__ out, int N) {
    __shared__ float sW[96 * 64];
    __shared__ float sb1[64];
    __shared__ float sW2[128];
    for (int i = threadIdx.x; i < 96 * 64; i += 256) sW[i] = Wf1[i];
    if (threadIdx.x < 64) sb1[threadIdx.x] = bf1[threadIdx.x];
    if (threadIdx.x < 128) sW2[threadIdx.x] = Wf2[threadIdx.x];
    __syncthreads();
    const int wave = threadIdx.x >> 6;
    const int lane = threadIdx.x & 63;
    for (int n = blockIdx.x * 4 + wave; n < N; n += gridDim.x * 4) {
        const float* gn = g2 + (size_t)n * 64;
        const float* tn = tt + (size_t)n * 32;
        float acc = sb1[lane];
#pragma unroll 8
        for (int k = 0; k < 64; k++) acc += gn[k] * sW[k * 64 + lane];
#pragma unroll 8
        for (int k = 0; k < 32; k++) acc += tn[k] * sW[(64 + k) * 64 + lane];
        acc = fmaxf(acc, 0.0f);
        float o0 = acc * sW2[lane * 2 + 0];
        float o1 = acc * sW2[lane * 2 + 1];
#pragma unroll
        for (int mk = 32; mk >= 1; mk >>= 1) {
            o0 += __shfl_xor(o0, mk);
            o1 += __shfl_xor(o1, mk);
        }
        if (lane == 0) {
            out[(size_t)n * 2 + 0] = o0 + bf2[0];
            out[(size_t)n * 2 + 1] = o1 + bf2[1];
        }
    }
}

extern "C" void kernel_launch(void* const* d_in, const int* in_sizes, int n_in,
                              void* d_out, int out_size, void* d_ws, size_t ws_size,
                              hipStream_t stream) {
    const float* x      = (const float*)d_in[0];
    const int*   eidx   = (const int*)d_in[1];
    const float* seq    = (const float*)d_in[2];
    const float* W1     = (const float*)d_in[3];
    const float* att_s1 = (const float*)d_in[4];
    const float* att_d1 = (const float*)d_in[5];
    const float* bias1  = (const float*)d_in[6];
    const float* W2     = (const float*)d_in[7];
    const float* att_s2 = (const float*)d_in[8];
    const float* att_d2 = (const float*)d_in[9];
    const float* bias2  = (const float*)d_in[10];
    const float* Wih    = (const float*)d_in[11];
    const float* Whh    = (const float*)d_in[12];
    const float* bih    = (const float*)d_in[13];
    const float* bhh    = (const float*)d_in[14];
    const float* Wf1    = (const float*)d_in[15];
    const float* bf1    = (const float*)d_in[16];
    const float* Wf2    = (const float*)d_in[17];
    const float* bf2    = (const float*)d_in[18];
    float* out = (float*)d_out;

    const int N  = in_sizes[0] / IN_F;   // 50000
    const int E  = in_sizes[1] / 2;      // 800000
    const int ET = E + N;
    const int* srcs = eidx;
    const int* dsts = eidx + E;

    // workspace layout
    float* fws = (float*)d_ws;
    size_t o = 0;
    float* h1  = fws + o; o += (size_t)N * 256;
    float* g1  = fws + o; o += (size_t)N * 256;
    float* as1 = fws + o; o += (size_t)N * 4;
    float* ad1 = fws + o; o += (size_t)N * 4;
    int* cnt    = (int*)(fws + o);
    int* rowp   = cnt + N;
    int* cursor = rowp + N + 1;
    int* eid    = cursor + N;
    int* bsum   = eid + ET;
    // layer-2 / LSTM aliases (h1 region dead after layer-1 aggregation)
    float* h2 = h1;                      // N*64
    float* g2 = h1 + (size_t)N * 64;     // N*64
    float* tt = h1 + (size_t)N * 128;    // N*32
    float* as2 = as1; float* ad2 = ad1;

    const int nTiles = (N + 255) / 256;
    dim3 blk(256);

    // ---- CSR build ----
    hipMemsetAsync(cnt, 0, (size_t)N * sizeof(int), stream);
    hipMemsetAsync(cursor, 0, (size_t)N * sizeof(int), stream);
    count_deg<<<(ET + 255) / 256, blk, 0, stream>>>(dsts, E, ET, cnt);
    scan1<<<nTiles, blk, 0, stream>>>(cnt, rowp, bsum, N);
    scan2<<<1, blk, 0, stream>>>(bsum, nTiles);
    scan3<<<(N + 256) / 256, blk, 0, stream>>>(rowp, bsum, N, ET);
    scatter_edges<<<(ET + 255) / 256, blk, 0, stream>>>(dsts, E, ET, rowp, cursor, eid);

    // ---- GAT layer 1 ----
    gemm64<128, 256><<<dim3((N + 63) / 64, 4), blk, 0, stream>>>(x, W1, h1, N);
    att_scores<<<(N * 4 + 255) / 256, blk, 0, stream>>>(h1, att_s1, att_d1, as1, ad1, N * 4, 3);
    gat_agg4_sp<<<(N + 3) / 4, blk, 0, stream>>>(srcs, E, rowp, eid, as1, ad1, h1, bias1, g1, N);

    // ---- LSTM (MFMA; reg-resident weights; tt region free once layer-1 agg done) ----
    lstm_mfma<<<(N + 63) / 64, dim3(512), 0, stream>>>(seq, Wih, Whh, bih, bhh, tt, N);

    // ---- GAT layer 2 ----
    gemm64<256, 64><<<dim3((N + 63) / 64, 1), blk, 0, stream>>>(g1, W2, h2, N);
    att_scores<<<(N + 255) / 256, blk, 0, stream>>>(h2, att_s2, att_d2, as2, ad2, N, 0);
    gat_agg1_sp<<<(N + 3) / 4, blk, 0, stream>>>(srcs, E, rowp, eid, as2, ad2, h2, bias2, g2, N);

    // ---- fusion MLP ----
    fusion_kernel<<<512, blk, 0, stream>>>(g2, tt, Wf1, bf1, Wf2, bf2, out, N);
}